// Round 2
// baseline (265.859 us; speedup 1.0000x reference)
//
#include <hip/hip_runtime.h>
#include <stdint.h>

// Factored algorithm:
//   ref: pre = [hs|hd|bond] @ W1^T + b1 + (hs+hd) @ W2^T + b2
//   =>  pre[e,o] = hs.(W1a[o]+W2[o]) + hd.(W1b[o]+W2[o]) + bond[e]*W1c[o] + (b1+b2)[o]
//   node tables: A = atom @ (W1a+W2)^T, B = atom @ (W1b+W2)^T   (N=10k << E=320k)
//   edge pass:   out[e] = leaky(A[src[e]] + B[dst[e]] + bond[e]*c + bias)
// Turns a 31.5 GFLOP edge GEMM into 0.65 GFLOP node GEMM + a write-bound gather.

// ---------------------------------------------------------------------------
// prep: fused weights (fp32 in / fp32 out).
//   Wf[256][128]: row o       : U[o][k] = W1[o,k]     + W2[o,k]
//                 row 128+o   : V[o][k] = W1[o,128+k] + W2[o,k]
//   cb[0:128]   = c[o]    = W1[o,256]
//   cb[128:256] = bias[o] = b1[o] + b2[o]
// ---------------------------------------------------------------------------
__global__ __launch_bounds__(256) void prep_kernel(
    const float* __restrict__ W1, const float* __restrict__ b1,
    const float* __restrict__ W2, const float* __restrict__ b2,
    float* __restrict__ Wf, float* __restrict__ cb)
{
    int idx = blockIdx.x * 256 + threadIdx.x;
    if (idx < 32768) {
        int r = idx >> 7, k = idx & 127;
        float w2 = W2[(r & 127) * 128 + k];
        float w1 = (r < 128) ? W1[r * 257 + k]
                             : W1[(r - 128) * 257 + 128 + k];
        Wf[idx] = w1 + w2;
    }
    if (idx < 128) {
        cb[idx]       = W1[idx * 257 + 256];
        cb[128 + idx] = b1[idx] + b2[idx];
    }
}

// ---------------------------------------------------------------------------
// node transform: A[n][o] = atom[n,:].U[o,:] ; B[n][o] = atom[n,:].V[o,:]
// 256 threads: thread t owns fused-weight row t (t<128 -> A, else B).
// 16 nodes per block; weight rows stream float4 (L2-hot); the 16 atom rows
// (8 KB) are block-uniform -> L1-hot after first wave.
// ---------------------------------------------------------------------------
__global__ __launch_bounds__(256) void node_kernel(
    const float* __restrict__ atom, const float* __restrict__ Wf,
    float* __restrict__ A, float* __restrict__ B, int N)
{
    const int t = threadIdx.x;
    const float4* __restrict__ wrow = (const float4*)(Wf + t * 128);
    const float4* __restrict__ arows = (const float4*)atom;
    const int base = blockIdx.x * 16;
    if (base >= N) return;

    float acc[16];
#pragma unroll
    for (int n = 0; n < 16; ++n) acc[n] = 0.f;

#pragma unroll 2
    for (int kc = 0; kc < 32; ++kc) {
        float4 w = wrow[kc];
#pragma unroll
        for (int n = 0; n < 16; ++n) {
            int row = base + n;
            if (row >= N) row = N - 1;  // clamp: harmless duplicate work
            float4 a = arows[(size_t)row * 32 + kc];
            acc[n] += w.x * a.x + w.y * a.y + w.z * a.z + w.w * a.w;
        }
    }

    float* outp = (t < 128) ? A : B;
    const int o = t & 127;
#pragma unroll
    for (int n = 0; n < 16; ++n) {
        int row = base + n;
        if (row < N) outp[(size_t)row * 128 + o] = acc[n];
    }
}

// ---------------------------------------------------------------------------
// edge pass: out[e,:] = leaky(A[src[e]] + B[dst[e]] + bond[e]*c + bias)
// 32 lanes per edge, 8 edges per 256-thread block; each lane does one float4
// of the 128-wide row -> 512 B contiguous store per edge row.
// ---------------------------------------------------------------------------
__global__ __launch_bounds__(256) void edge_kernel(
    const int* __restrict__ src, const int* __restrict__ dst,
    const float* __restrict__ bond,
    const float* __restrict__ A, const float* __restrict__ B,
    const float* __restrict__ cb, float4* __restrict__ out, int E)
{
    const int g = threadIdx.x >> 5;
    const int l = threadIdx.x & 31;
    const int e = blockIdx.x * 8 + g;
    if (e >= E) return;

    const int s = src[e];          // same addr across the 32-lane group:
    const int d = dst[e];          // broadcast, L1-served
    const float bv = bond[e];

    float4 a  = ((const float4*)A)[(size_t)s * 32 + l];
    float4 b  = ((const float4*)B)[(size_t)d * 32 + l];
    float4 c  = ((const float4*)cb)[l];
    float4 bi = ((const float4*)cb)[32 + l];

    float4 x;
    x.x = a.x + b.x + bv * c.x + bi.x;
    x.y = a.y + b.y + bv * c.y + bi.y;
    x.z = a.z + b.z + bv * c.z + bi.z;
    x.w = a.w + b.w + bv * c.w + bi.w;
    x.x = x.x > 0.f ? x.x : 0.01f * x.x;
    x.y = x.y > 0.f ? x.y : 0.01f * x.y;
    x.z = x.z > 0.f ? x.z : 0.01f * x.z;
    x.w = x.w > 0.f ? x.w : 0.01f * x.w;

    out[(size_t)e * 32 + l] = x;
}

// ---------------------------------------------------------------------------
extern "C" void kernel_launch(void* const* d_in, const int* in_sizes, int n_in,
                              void* d_out, int out_size, void* d_ws, size_t ws_size,
                              hipStream_t stream)
{
    const float* atom = (const float*)d_in[0];  // [N,128] fp32
    const float* bond = (const float*)d_in[1];  // [E,1]  fp32
    const int*   src  = (const int*)d_in[2];    // [E]
    const int*   dst  = (const int*)d_in[3];    // [E]
    const float* W1   = (const float*)d_in[4];  // [128,257] fp32
    const float* b1   = (const float*)d_in[5];  // [128]
    const float* W2   = (const float*)d_in[6];  // [128,128] fp32
    const float* b2   = (const float*)d_in[7];  // [128]

    const int N = in_sizes[0] / 128;
    const int E = in_sizes[2];

    // workspace layout (fp32): Wf[256*128] | cb[256] | A[N*128] | B[N*128]
    // total = (32768 + 256 + 2*N*128)*4 B ~= 10.4 MB for N=10000
    float* Wf = (float*)d_ws;
    float* cb = Wf + 32768;
    float* A  = cb + 256;
    float* B  = A + (size_t)N * 128;

    prep_kernel<<<128, 256, 0, stream>>>(W1, b1, W2, b2, Wf, cb);
    node_kernel<<<(N + 15) / 16, 256, 0, stream>>>(atom, Wf, A, B, N);
    edge_kernel<<<(E + 7) / 8, 256, 0, stream>>>(src, dst, bond, A, B, cb,
                                                 (float4*)d_out, E);
}